// Round 11
// baseline (532.986 us; speedup 1.0000x reference)
//
#include <hip/hip_runtime.h>
#include <hip/hip_bf16.h>
#include <math.h>

#define BATCH 8
#define NNODE 4096
#define DEG 16
#define DIN 64
#define DM 128
#define NH 4
#define DHD 32
#define BN (BATCH*NNODE)   // 32768
#define NLAYERS 3
#define NN_SCALE 1999853.335557038f

// workspace layout (float offsets)
#define X_OFF     0
#define H_OFF     (BN*DM)            // 4194304
#define AGG_OFF   (2*BN*DM)          // 8388608
#define WLP_OFF   (3*BN*DM)          // 12582912
#define WCOMB_OFF (WLP_OFF + NLAYERS*DM*DM)

__device__ __forceinline__ float elu_f(float x) {
  return x > 0.f ? x : expm1f(x);
}

// ---------------------------------------------------------------------------
// Prep: Wl -> plain [d][c] layout;  Wcomb = blockdiag(Wo) @ Wlin  (128x128)
// ---------------------------------------------------------------------------
__global__ __launch_bounds__(256) void prep_kernel(
    const float* __restrict__ Wl, const float* __restrict__ Wo,
    const float* __restrict__ Wlin, float* __restrict__ ws) {
  const int bid = blockIdx.x;          // 48 blocks: l = bid>>4, slice = bid&15
  const int l = bid >> 4, sl = bid & 15;
  float* Wlp = ws + WLP_OFF   + l*DM*DM;
  float* Wcb = ws + WCOMB_OFF + l*DM*DM;
  const float* Wl_l   = Wl   + l*NH*DM*DHD;   // [h][d][k]
  const float* Wo_l   = Wo   + l*NH*DHD*DHD;  // [h][k][o]
  const float* Wlin_l = Wlin + l*DM*DM;       // [c'][d]
  for (int idx = sl*1024 + threadIdx.x; idx < (sl+1)*1024; idx += 256) {
    int d = idx >> 7, c = idx & 127;
    Wlp[idx] = Wl_l[((c>>5)*DM + d)*DHD + (c&31)];
  }
  for (int idx = sl*1024 + threadIdx.x; idx < (sl+1)*1024; idx += 256) {
    int r = idx >> 7, dcol = idx & 127;
    int h = r >> 5, k = r & 31;
    const float* wo  = Wo_l + (h*DHD + k)*DHD;      // over o
    const float* wl2 = Wlin_l + (h*DHD)*DM + dcol;  // stride DM over o
    float acc = 0.f;
    #pragma unroll
    for (int o = 0; o < DHD; o++) acc = fmaf(wo[o], wl2[o*DM], acc);
    Wcb[idx] = acc;
  }
}

// ---------------------------------------------------------------------------
// Tall GEMM: out[M=BN x 128] = A[BN x K] @ W[K x 128]  (+ epilogue)
// EPI 0: plain store; 1: +bias, ELU; 2: +bias, ELU, +residual, LayerNorm
// Block: 128 threads = 8(i rowgrp) x 16(j colgrp); 8 rows x 8 cols / thread.
// Block tile 64 x 128. LDS rows padded so every row start is 16B-aligned:
//   xT stride 68 (272B), Wc stride 132 (528B).
// ---------------------------------------------------------------------------
template<int K, int EPI>
__global__ __launch_bounds__(128) void gemm_kernel(
    const float* __restrict__ A, const float* __restrict__ W,
    const float* __restrict__ bias, const float* __restrict__ lng,
    const float* __restrict__ lnb, const float* __restrict__ res,
    float* __restrict__ out) {
  __shared__ float xT[32][68];    // transposed A chunk (k x row)
  __shared__ float Wc[32][132];   // W chunk (k x col)
  const int tid = threadIdx.x;
  const int j = tid & 15, i = tid >> 4;     // i 0..7, j 0..15
  const int row0 = blockIdx.x * 64;

  float acc[8][8];
  #pragma unroll
  for (int a = 0; a < 8; a++)
    #pragma unroll
    for (int b = 0; b < 8; b++) acc[a][b] = 0.f;

  float bval[8], gv[8], bv2[8];
  if (EPI != 0) {
    #pragma unroll
    for (int cc = 0; cc < 8; cc++) bval[cc] = bias[j*8 + cc];
  }
  if (EPI == 2) {
    #pragma unroll
    for (int cc = 0; cc < 8; cc++) { gv[cc] = lng[j*8+cc]; bv2[cc] = lnb[j*8+cc]; }
  }

  const int kq = tid & 7, rb = tid >> 3;    // staging coords: rb 0..15

  for (int k0 = 0; k0 < K; k0 += 32) {
    // stage A chunk (64 rows x 32 k), transposed scatter
    #pragma unroll
    for (int p = 0; p < 4; p++) {
      const int r = rb + p*16;
      const float4 v = *reinterpret_cast<const float4*>(
          &A[(size_t)(row0 + r)*K + k0 + kq*4]);
      xT[kq*4+0][r] = v.x; xT[kq*4+1][r] = v.y;
      xT[kq*4+2][r] = v.z; xT[kq*4+3][r] = v.w;
    }
    // stage W chunk (32 k x 128 cols)
    #pragma unroll
    for (int p = 0; p < 8; p++) {
      const int idx = p*128 + tid;          // 0..1023 float4 quads
      const int d = idx >> 5, cq = idx & 31;
      *reinterpret_cast<float4*>(&Wc[d][cq*4]) =
          *reinterpret_cast<const float4*>(&W[(size_t)(k0 + d)*128 + cq*4]);
    }
    __syncthreads();
    #pragma unroll
    for (int kk = 0; kk < 32; kk++) {
      const float4 a0 = *reinterpret_cast<const float4*>(&xT[kk][i*8]);
      const float4 a1 = *reinterpret_cast<const float4*>(&xT[kk][i*8+4]);
      const float av[8] = {a0.x,a0.y,a0.z,a0.w,a1.x,a1.y,a1.z,a1.w};
      const float4 w0 = *reinterpret_cast<const float4*>(&Wc[kk][j*8]);
      const float4 w1 = *reinterpret_cast<const float4*>(&Wc[kk][j*8+4]);
      const float wv[8] = {w0.x,w0.y,w0.z,w0.w,w1.x,w1.y,w1.z,w1.w};
      #pragma unroll
      for (int rr = 0; rr < 8; rr++)
        #pragma unroll
        for (int cc = 0; cc < 8; cc++)
          acc[rr][cc] = fmaf(av[rr], wv[cc], acc[rr][cc]);
    }
    __syncthreads();
  }

  if (EPI == 0) {
    #pragma unroll
    for (int rr = 0; rr < 8; rr++) {
      float* op = out + (size_t)(row0 + i*8 + rr)*DM + j*8;
      float4 v0 = {acc[rr][0],acc[rr][1],acc[rr][2],acc[rr][3]};
      float4 v1 = {acc[rr][4],acc[rr][5],acc[rr][6],acc[rr][7]};
      *reinterpret_cast<float4*>(op)     = v0;
      *reinterpret_cast<float4*>(op + 4) = v1;
    }
  } else if (EPI == 1) {
    #pragma unroll
    for (int rr = 0; rr < 8; rr++) {
      float* op = out + (size_t)(row0 + i*8 + rr)*DM + j*8;
      float4 v0, v1;
      v0.x = elu_f(acc[rr][0]+bval[0]); v0.y = elu_f(acc[rr][1]+bval[1]);
      v0.z = elu_f(acc[rr][2]+bval[2]); v0.w = elu_f(acc[rr][3]+bval[3]);
      v1.x = elu_f(acc[rr][4]+bval[4]); v1.y = elu_f(acc[rr][5]+bval[5]);
      v1.z = elu_f(acc[rr][6]+bval[6]); v1.w = elu_f(acc[rr][7]+bval[7]);
      *reinterpret_cast<float4*>(op)     = v0;
      *reinterpret_cast<float4*>(op + 4) = v1;
    }
  } else {
    float s[8], s2[8];
    #pragma unroll
    for (int rr = 0; rr < 8; rr++) {
      const int r = row0 + i*8 + rr;
      const float4 r0 = *reinterpret_cast<const float4*>(&res[(size_t)r*DM + j*8]);
      const float4 r1 = *reinterpret_cast<const float4*>(&res[(size_t)r*DM + j*8 + 4]);
      const float rv[8] = {r0.x,r0.y,r0.z,r0.w,r1.x,r1.y,r1.z,r1.w};
      s[rr] = 0.f; s2[rr] = 0.f;
      #pragma unroll
      for (int cc = 0; cc < 8; cc++) {
        float v = elu_f(acc[rr][cc] + bval[cc]) + rv[cc];
        acc[rr][cc] = v; s[rr] += v; s2[rr] += v*v;
      }
    }
    #pragma unroll
    for (int o = 1; o < 16; o <<= 1) {
      #pragma unroll
      for (int rr = 0; rr < 8; rr++) {
        s[rr]  += __shfl_xor(s[rr],  o);
        s2[rr] += __shfl_xor(s2[rr], o);
      }
    }
    #pragma unroll
    for (int rr = 0; rr < 8; rr++) {
      const int r = row0 + i*8 + rr;
      const float mu  = s[rr] * (1.f/128.f);
      const float var = s2[rr] * (1.f/128.f) - mu*mu;
      const float rs  = rsqrtf(var + 1e-5f);
      float4 v0, v1;
      v0.x = (acc[rr][0]-mu)*rs*gv[0] + bv2[0];
      v0.y = (acc[rr][1]-mu)*rs*gv[1] + bv2[1];
      v0.z = (acc[rr][2]-mu)*rs*gv[2] + bv2[2];
      v0.w = (acc[rr][3]-mu)*rs*gv[3] + bv2[3];
      v1.x = (acc[rr][4]-mu)*rs*gv[4] + bv2[4];
      v1.y = (acc[rr][5]-mu)*rs*gv[5] + bv2[5];
      v1.z = (acc[rr][6]-mu)*rs*gv[6] + bv2[6];
      v1.w = (acc[rr][7]-mu)*rs*gv[7] + bv2[7];
      float* op = out + (size_t)r*DM + j*8;
      *reinterpret_cast<float4*>(op)     = v0;
      *reinterpret_cast<float4*>(op + 4) = v1;
    }
  }
}

// ---------------------------------------------------------------------------
// Attention: one wave per node. lane = m*4 + h (m neighbor, h head).
// Neighbor slice h[adj][h*32..+31] in registers; agg via shfl reduce-scatter.
// ---------------------------------------------------------------------------
__global__ __launch_bounds__(256) void attn_kernel(
    const float* __restrict__ h, const int* __restrict__ adj,
    const float* __restrict__ masks, const float* __restrict__ a_src,
    const float* __restrict__ a_dst, float* __restrict__ agg) {
  const int lane = threadIdx.x & 63;
  const int wid  = threadIdx.x >> 6;
  const int node = blockIdx.x*4 + wid;      // < 32768
  const int b = node >> 12;
  const int hh = lane & 3;
  const int m  = lane >> 2;

  // per-lane constant a_dst row for head hh
  float ad[32];
  {
    const float4* p = reinterpret_cast<const float4*>(a_dst + hh*DHD);
    #pragma unroll
    for (int q = 0; q < 8; q++) {
      float4 v = p[q];
      ad[4*q]=v.x; ad[4*q+1]=v.y; ad[4*q+2]=v.z; ad[4*q+3]=v.w;
    }
  }

  // e_src: cooperative dot over own h row (elements 2*lane, 2*lane+1)
  const int eh = lane >> 4;
  const float2 asr = *reinterpret_cast<const float2*>(a_src + eh*DHD + 2*(lane & 15));
  const float2 hv  = reinterpret_cast<const float2*>(h + (size_t)node*DM)[lane];
  float esp = hv.x*asr.x + hv.y*asr.y;
  esp += __shfl_xor(esp, 1); esp += __shfl_xor(esp, 2);
  esp += __shfl_xor(esp, 4); esp += __shfl_xor(esp, 8);
  const float es = __shfl(esp, hh << 4);

  // gather neighbor slice
  const int   jn   = adj[node*DEG + m];
  const float mval = masks[node*DEG + m];
  const float4* hp = reinterpret_cast<const float4*>(
      h + ((size_t)(b*NNODE + jn))*DM + hh*DHD);
  float hn[32];
  #pragma unroll
  for (int q = 0; q < 8; q++) {
    float4 v = hp[q];
    hn[4*q]=v.x; hn[4*q+1]=v.y; hn[4*q+2]=v.z; hn[4*q+3]=v.w;
  }
  float ed = 0.f;
  #pragma unroll
  for (int k = 0; k < 32; k++) ed = fmaf(hn[k], ad[k], ed);

  float e = es + ed;
  e = e > 0.f ? e : 0.2f*e;           // leaky_relu 0.2
  e = (mval > 0.f) ? e : -1e9f;       // mask

  // softmax over m (lanes stride 4)
  float mx = e;
  mx = fmaxf(mx, __shfl_xor(mx, 4));  mx = fmaxf(mx, __shfl_xor(mx, 8));
  mx = fmaxf(mx, __shfl_xor(mx, 16)); mx = fmaxf(mx, __shfl_xor(mx, 32));
  const float pe = __expf(e - mx);
  float sm = pe;
  sm += __shfl_xor(sm, 4);  sm += __shfl_xor(sm, 8);
  sm += __shfl_xor(sm, 16); sm += __shfl_xor(sm, 32);
  const float alpha = pe / sm;

  #pragma unroll
  for (int k = 0; k < 32; k++) hn[k] *= alpha;

  // reduce-scatter over the 16 m-lanes: lane ends with k = {k0, k0+1}
  float v16[16], v8[8], v4[4], v2[2];
  {
    const bool bb = (lane & 4) != 0;
    #pragma unroll
    for (int q = 0; q < 16; q++) {
      float keep = bb ? hn[16+q] : hn[q];
      float send = bb ? hn[q]    : hn[16+q];
      v16[q] = keep + __shfl_xor(send, 4);
    }
  }
  {
    const bool bb = (lane & 8) != 0;
    #pragma unroll
    for (int q = 0; q < 8; q++) {
      float keep = bb ? v16[8+q] : v16[q];
      float send = bb ? v16[q]   : v16[8+q];
      v8[q] = keep + __shfl_xor(send, 8);
    }
  }
  {
    const bool bb = (lane & 16) != 0;
    #pragma unroll
    for (int q = 0; q < 4; q++) {
      float keep = bb ? v8[4+q] : v8[q];
      float send = bb ? v8[q]   : v8[4+q];
      v4[q] = keep + __shfl_xor(send, 16);
    }
  }
  {
    const bool bb = (lane & 32) != 0;
    #pragma unroll
    for (int q = 0; q < 2; q++) {
      float keep = bb ? v4[2+q] : v4[q];
      float send = bb ? v4[q]   : v4[2+q];
      v2[q] = keep + __shfl_xor(send, 32);
    }
  }
  const int k0 = ((m&1)<<4) | ((m&2)<<2) | (m&4) | ((m&8)>>2);
  float2 st; st.x = v2[0]; st.y = v2[1];
  *reinterpret_cast<float2*>(agg + (size_t)node*DM + hh*DHD + k0) = st;
}

// ---------------------------------------------------------------------------
// Final query MLP: 8 rows, 128->256->128->8, ELU, * NN_SCALE
// ---------------------------------------------------------------------------
__global__ __launch_bounds__(256) void mlp_kernel(
    const float* __restrict__ x, const int* __restrict__ qidx,
    const float* __restrict__ Wf1, const float* __restrict__ bf1,
    const float* __restrict__ Wf2, const float* __restrict__ bf2,
    const float* __restrict__ Wf3, const float* __restrict__ bf3,
    float* __restrict__ out) {
  __shared__ float xv[128];
  __shared__ float y1[256];
  __shared__ float y2[128];
  const int b = blockIdx.x, t = threadIdx.x;
  const int qi = qidx[b];
  if (t < 128) xv[t] = x[((size_t)b*NNODE + qi)*DM + t];
  __syncthreads();
  {
    float a1 = bf1[t];
    #pragma unroll 8
    for (int d = 0; d < 128; d++) a1 = fmaf(xv[d], Wf1[d*256 + t], a1);
    y1[t] = elu_f(a1);
  }
  __syncthreads();
  if (t < 128) {
    float a2 = bf2[t];
    #pragma unroll 8
    for (int d = 0; d < 256; d++) a2 = fmaf(y1[d], Wf2[d*128 + t], a2);
    y2[t] = elu_f(a2);
  }
  __syncthreads();
  if (t < 8) {
    float a3 = bf3[t];
    #pragma unroll 8
    for (int d = 0; d < 128; d++) a3 = fmaf(y2[d], Wf3[d*8 + t], a3);
    out[b*8 + t] = elu_f(a3) * NN_SCALE;
  }
}

// ---------------------------------------------------------------------------
extern "C" void kernel_launch(void* const* d_in, const int* in_sizes, int n_in,
                              void* d_out, int out_size, void* d_ws, size_t ws_size,
                              hipStream_t stream) {
  (void)in_sizes; (void)n_in; (void)out_size; (void)ws_size;
  const float* nf    = (const float*)d_in[0];
  const int*   qidx  = (const int*)d_in[1];
  const float* masks = (const float*)d_in[2];
  const int*   adj   = (const int*)d_in[3];
  // d_in[4] sim_results: unused by the reference
  const float* W0    = (const float*)d_in[5];
  const float* b0    = (const float*)d_in[6];
  const float* Wl    = (const float*)d_in[7];
  const float* a_src = (const float*)d_in[8];
  const float* a_dst = (const float*)d_in[9];
  const float* Wo    = (const float*)d_in[10];
  const float* Wlin  = (const float*)d_in[11];
  const float* blin  = (const float*)d_in[12];
  const float* ln_g  = (const float*)d_in[13];
  const float* ln_b  = (const float*)d_in[14];
  const float* Wf1   = (const float*)d_in[15];
  const float* bf1   = (const float*)d_in[16];
  const float* Wf2   = (const float*)d_in[17];
  const float* bf2   = (const float*)d_in[18];
  const float* Wf3   = (const float*)d_in[19];
  const float* bf3   = (const float*)d_in[20];

  float* ws  = (float*)d_ws;
  float* x   = ws + X_OFF;
  float* h   = ws + H_OFF;
  float* agg = ws + AGG_OFF;

  prep_kernel<<<48, 256, 0, stream>>>(Wl, Wo, Wlin, ws);

  // x = elu(nf @ W0 + b0)
  gemm_kernel<DIN, 1><<<BN/64, 128, 0, stream>>>(
      nf, W0, b0, nullptr, nullptr, nullptr, x);

  for (int l = 0; l < NLAYERS; l++) {
    const float* Wlp = ws + WLP_OFF   + l*DM*DM;
    const float* Wcb = ws + WCOMB_OFF + l*DM*DM;
    // h = x @ Wl  (all heads)
    gemm_kernel<DM, 0><<<BN/64, 128, 0, stream>>>(
        x, Wlp, nullptr, nullptr, nullptr, nullptr, h);
    // agg = GAT attention aggregate
    attn_kernel<<<BN/4, 256, 0, stream>>>(
        h, adj, masks, a_src + l*NH*DHD, a_dst + l*NH*DHD, agg);
    // x = LN(elu(agg @ Wcomb + blin) + x)
    gemm_kernel<DM, 2><<<BN/64, 128, 0, stream>>>(
        agg, Wcb, blin + l*DM, ln_g + l*DM, ln_b + l*DM, x, x);
  }

  mlp_kernel<<<8, 256, 0, stream>>>(
      x, qidx, Wf1, bf1, Wf2, bf2, Wf3, bf3, (float*)d_out);
}

// Round 12
// 479.769 us; speedup vs baseline: 1.1109x; 1.1109x over previous
//
#include <hip/hip_runtime.h>
#include <hip/hip_bf16.h>
#include <math.h>

#define BATCH 8
#define NNODE 4096
#define DEG 16
#define DIN 64
#define DM 128
#define NH 4
#define DHD 32
#define BN (BATCH*NNODE)   // 32768
#define NLAYERS 3
#define NN_SCALE 1999853.335557038f

// workspace layout (float offsets)
#define X_OFF     0
#define H_OFF     (BN*DM)
#define AGG_OFF   (2*BN*DM)
#define WLP_OFF   (3*BN*DM)
#define WCOMB_OFF (WLP_OFF + NLAYERS*DM*DM)

__device__ __forceinline__ float elu_f(float x) {
  return x > 0.f ? x : expm1f(x);
}

// ---------------------------------------------------------------------------
// Prep: Wl -> plain [d][c] layout;  Wcomb = blockdiag(Wo) @ Wlin  (128x128)
// ---------------------------------------------------------------------------
__global__ __launch_bounds__(256) void prep_kernel(
    const float* __restrict__ Wl, const float* __restrict__ Wo,
    const float* __restrict__ Wlin, float* __restrict__ ws) {
  const int bid = blockIdx.x;          // 48 blocks: l = bid>>4, slice = bid&15
  const int l = bid >> 4, sl = bid & 15;
  float* Wlp = ws + WLP_OFF   + l*DM*DM;
  float* Wcb = ws + WCOMB_OFF + l*DM*DM;
  const float* Wl_l   = Wl   + l*NH*DM*DHD;   // [h][d][k]
  const float* Wo_l   = Wo   + l*NH*DHD*DHD;  // [h][k][o]
  const float* Wlin_l = Wlin + l*DM*DM;       // [c'][d]
  for (int idx = sl*1024 + threadIdx.x; idx < (sl+1)*1024; idx += 256) {
    int d = idx >> 7, c = idx & 127;
    Wlp[idx] = Wl_l[((c>>5)*DM + d)*DHD + (c&31)];
  }
  for (int idx = sl*1024 + threadIdx.x; idx < (sl+1)*1024; idx += 256) {
    int r = idx >> 7, dcol = idx & 127;
    int h = r >> 5, k = r & 31;
    const float* wo  = Wo_l + (h*DHD + k)*DHD;      // over o
    const float* wl2 = Wlin_l + (h*DHD)*DM + dcol;  // stride DM over o
    float acc = 0.f;
    #pragma unroll
    for (int o = 0; o < DHD; o++) acc = fmaf(wo[o], wl2[o*DM], acc);
    Wcb[idx] = acc;
  }
}

// ---------------------------------------------------------------------------
// Tall GEMM: out[M=BN x 128] = A[BN x K] @ W[K x 128]  (+ epilogue)
// EPI 0: plain store; 1: +bias, ELU; 2: +bias, ELU, +residual, LayerNorm
// v2: 32-row tiles, grid 1024 (4 blocks/CU -> 2 waves/SIMD; was 1).
// XCD-clustered: bid&7 selects batch => batch slice stays in that XCD's L2.
// 128 thr = 8(i) x 16(j); 4 rows x 8 cols per thread.
// ---------------------------------------------------------------------------
template<int K, int EPI>
__global__ __launch_bounds__(128) void gemm_kernel(
    const float* __restrict__ A, const float* __restrict__ W,
    const float* __restrict__ bias, const float* __restrict__ lng,
    const float* __restrict__ lnb, const float* __restrict__ res,
    float* __restrict__ out) {
  __shared__ float xT[32][36];    // transposed A chunk (k x row), 144B rows
  __shared__ float Wc[32][132];   // W chunk (k x col), 528B rows
  const int tid = threadIdx.x;
  const int j = tid & 15, i = tid >> 4;     // i 0..7, j 0..15
  // XCD-clustered tile map: 1024 blocks, 128 tiles/batch, batch = bid&7
  const int bid  = blockIdx.x;
  const int row0 = ((bid & 7) * 128 + (bid >> 3)) * 32;

  float acc[4][8];
  #pragma unroll
  for (int a = 0; a < 4; a++)
    #pragma unroll
    for (int b = 0; b < 8; b++) acc[a][b] = 0.f;

  float bval[8], gv[8], bv2[8];
  if (EPI != 0) {
    #pragma unroll
    for (int cc = 0; cc < 8; cc++) bval[cc] = bias[j*8 + cc];
  }
  if (EPI == 2) {
    #pragma unroll
    for (int cc = 0; cc < 8; cc++) { gv[cc] = lng[j*8+cc]; bv2[cc] = lnb[j*8+cc]; }
  }

  const int kq = tid & 7, rb = tid >> 3;    // staging: rb 0..15

  for (int k0 = 0; k0 < K; k0 += 32) {
    // stage A chunk (32 rows x 32 k), transposed scatter: 2 rows/thread
    #pragma unroll
    for (int p = 0; p < 2; p++) {
      const int r = rb + p*16;
      const float4 v = *reinterpret_cast<const float4*>(
          &A[(size_t)(row0 + r)*K + k0 + kq*4]);
      xT[kq*4+0][r] = v.x; xT[kq*4+1][r] = v.y;
      xT[kq*4+2][r] = v.z; xT[kq*4+3][r] = v.w;
    }
    // stage W chunk (32 k x 128 cols)
    #pragma unroll
    for (int p = 0; p < 8; p++) {
      const int idx = p*128 + tid;
      const int d = idx >> 5, cq = idx & 31;
      *reinterpret_cast<float4*>(&Wc[d][cq*4]) =
          *reinterpret_cast<const float4*>(&W[(size_t)(k0 + d)*128 + cq*4]);
    }
    __syncthreads();
    #pragma unroll
    for (int kk = 0; kk < 32; kk++) {
      const float4 a0 = *reinterpret_cast<const float4*>(&xT[kk][i*4]);
      const float av[4] = {a0.x, a0.y, a0.z, a0.w};
      const float4 w0 = *reinterpret_cast<const float4*>(&Wc[kk][j*8]);
      const float4 w1 = *reinterpret_cast<const float4*>(&Wc[kk][j*8+4]);
      const float wv[8] = {w0.x,w0.y,w0.z,w0.w,w1.x,w1.y,w1.z,w1.w};
      #pragma unroll
      for (int rr = 0; rr < 4; rr++)
        #pragma unroll
        for (int cc = 0; cc < 8; cc++)
          acc[rr][cc] = fmaf(av[rr], wv[cc], acc[rr][cc]);
    }
    __syncthreads();
  }

  if (EPI == 0) {
    #pragma unroll
    for (int rr = 0; rr < 4; rr++) {
      float* op = out + (size_t)(row0 + i*4 + rr)*DM + j*8;
      float4 v0 = {acc[rr][0],acc[rr][1],acc[rr][2],acc[rr][3]};
      float4 v1 = {acc[rr][4],acc[rr][5],acc[rr][6],acc[rr][7]};
      *reinterpret_cast<float4*>(op)     = v0;
      *reinterpret_cast<float4*>(op + 4) = v1;
    }
  } else if (EPI == 1) {
    #pragma unroll
    for (int rr = 0; rr < 4; rr++) {
      float* op = out + (size_t)(row0 + i*4 + rr)*DM + j*8;
      float4 v0, v1;
      v0.x = elu_f(acc[rr][0]+bval[0]); v0.y = elu_f(acc[rr][1]+bval[1]);
      v0.z = elu_f(acc[rr][2]+bval[2]); v0.w = elu_f(acc[rr][3]+bval[3]);
      v1.x = elu_f(acc[rr][4]+bval[4]); v1.y = elu_f(acc[rr][5]+bval[5]);
      v1.z = elu_f(acc[rr][6]+bval[6]); v1.w = elu_f(acc[rr][7]+bval[7]);
      *reinterpret_cast<float4*>(op)     = v0;
      *reinterpret_cast<float4*>(op + 4) = v1;
    }
  } else {
    float s[4], s2[4];
    #pragma unroll
    for (int rr = 0; rr < 4; rr++) {
      const int r = row0 + i*4 + rr;
      const float4 r0 = *reinterpret_cast<const float4*>(&res[(size_t)r*DM + j*8]);
      const float4 r1 = *reinterpret_cast<const float4*>(&res[(size_t)r*DM + j*8 + 4]);
      const float rv[8] = {r0.x,r0.y,r0.z,r0.w,r1.x,r1.y,r1.z,r1.w};
      s[rr] = 0.f; s2[rr] = 0.f;
      #pragma unroll
      for (int cc = 0; cc < 8; cc++) {
        float v = elu_f(acc[rr][cc] + bval[cc]) + rv[cc];
        acc[rr][cc] = v; s[rr] += v; s2[rr] += v*v;
      }
    }
    #pragma unroll
    for (int o = 1; o < 16; o <<= 1) {
      #pragma unroll
      for (int rr = 0; rr < 4; rr++) {
        s[rr]  += __shfl_xor(s[rr],  o);
        s2[rr] += __shfl_xor(s2[rr], o);
      }
    }
    #pragma unroll
    for (int rr = 0; rr < 4; rr++) {
      const int r = row0 + i*4 + rr;
      const float mu  = s[rr] * (1.f/128.f);
      const float var = s2[rr] * (1.f/128.f) - mu*mu;
      const float rs  = rsqrtf(var + 1e-5f);
      float4 v0, v1;
      v0.x = (acc[rr][0]-mu)*rs*gv[0] + bv2[0];
      v0.y = (acc[rr][1]-mu)*rs*gv[1] + bv2[1];
      v0.z = (acc[rr][2]-mu)*rs*gv[2] + bv2[2];
      v0.w = (acc[rr][3]-mu)*rs*gv[3] + bv2[3];
      v1.x = (acc[rr][4]-mu)*rs*gv[4] + bv2[4];
      v1.y = (acc[rr][5]-mu)*rs*gv[5] + bv2[5];
      v1.z = (acc[rr][6]-mu)*rs*gv[6] + bv2[6];
      v1.w = (acc[rr][7]-mu)*rs*gv[7] + bv2[7];
      float* op = out + (size_t)r*DM + j*8;
      *reinterpret_cast<float4*>(op)     = v0;
      *reinterpret_cast<float4*>(op + 4) = v1;
    }
  }
}

// ---------------------------------------------------------------------------
// Attention: one wave per node. lane = m*4 + h.
// XCD-clustered: bid&7 = batch (matches GEMM), so h-slice (2.1 MB) and agg
// slice live in that XCD's 4 MB L2 -> gathers become local-L2 hits.
// ---------------------------------------------------------------------------
__global__ __launch_bounds__(256) void attn_kernel(
    const float* __restrict__ h, const int* __restrict__ adj,
    const float* __restrict__ masks, const float* __restrict__ a_src,
    const float* __restrict__ a_dst, float* __restrict__ agg) {
  const int lane = threadIdx.x & 63;
  const int wid  = threadIdx.x >> 6;
  const int bid  = blockIdx.x;                       // 8192 blocks
  const int node = ((bid & 7) << 12) + ((bid >> 3) << 2) + wid;
  const int b = node >> 12;
  const int hh = lane & 3;
  const int m  = lane >> 2;

  // per-lane constant a_dst row for head hh
  float ad[32];
  {
    const float4* p = reinterpret_cast<const float4*>(a_dst + hh*DHD);
    #pragma unroll
    for (int q = 0; q < 8; q++) {
      float4 v = p[q];
      ad[4*q]=v.x; ad[4*q+1]=v.y; ad[4*q+2]=v.z; ad[4*q+3]=v.w;
    }
  }

  // e_src: cooperative dot over own h row
  const int eh = lane >> 4;
  const float2 asr = *reinterpret_cast<const float2*>(a_src + eh*DHD + 2*(lane & 15));
  const float2 hv  = reinterpret_cast<const float2*>(h + (size_t)node*DM)[lane];
  float esp = hv.x*asr.x + hv.y*asr.y;
  esp += __shfl_xor(esp, 1); esp += __shfl_xor(esp, 2);
  esp += __shfl_xor(esp, 4); esp += __shfl_xor(esp, 8);
  const float es = __shfl(esp, hh << 4);

  // gather neighbor slice
  const int   jn   = adj[node*DEG + m];
  const float mval = masks[node*DEG + m];
  const float4* hp = reinterpret_cast<const float4*>(
      h + ((size_t)(b*NNODE + jn))*DM + hh*DHD);
  float hn[32];
  #pragma unroll
  for (int q = 0; q < 8; q++) {
    float4 v = hp[q];
    hn[4*q]=v.x; hn[4*q+1]=v.y; hn[4*q+2]=v.z; hn[4*q+3]=v.w;
  }
  float ed = 0.f;
  #pragma unroll
  for (int k = 0; k < 32; k++) ed = fmaf(hn[k], ad[k], ed);

  float e = es + ed;
  e = e > 0.f ? e : 0.2f*e;           // leaky_relu 0.2
  e = (mval > 0.f) ? e : -1e9f;       // mask

  // softmax over m (lanes stride 4)
  float mx = e;
  mx = fmaxf(mx, __shfl_xor(mx, 4));  mx = fmaxf(mx, __shfl_xor(mx, 8));
  mx = fmaxf(mx, __shfl_xor(mx, 16)); mx = fmaxf(mx, __shfl_xor(mx, 32));
  const float pe = __expf(e - mx);
  float sm = pe;
  sm += __shfl_xor(sm, 4);  sm += __shfl_xor(sm, 8);
  sm += __shfl_xor(sm, 16); sm += __shfl_xor(sm, 32);
  const float alpha = pe / sm;

  #pragma unroll
  for (int k = 0; k < 32; k++) hn[k] *= alpha;

  // reduce-scatter over the 16 m-lanes: lane ends with k = {k0, k0+1}
  float v16[16], v8[8], v4[4], v2[2];
  {
    const bool bb = (lane & 4) != 0;
    #pragma unroll
    for (int q = 0; q < 16; q++) {
      float keep = bb ? hn[16+q] : hn[q];
      float send = bb ? hn[q]    : hn[16+q];
      v16[q] = keep + __shfl_xor(send, 4);
    }
  }
  {
    const bool bb = (lane & 8) != 0;
    #pragma unroll
    for (int q = 0; q < 8; q++) {
      float keep = bb ? v16[8+q] : v16[q];
      float send = bb ? v16[q]   : v16[8+q];
      v8[q] = keep + __shfl_xor(send, 8);
    }
  }
  {
    const bool bb = (lane & 16) != 0;
    #pragma unroll
    for (int q = 0; q < 4; q++) {
      float keep = bb ? v8[4+q] : v8[q];
      float send = bb ? v8[q]   : v8[4+q];
      v4[q] = keep + __shfl_xor(send, 16);
    }
  }
  {
    const bool bb = (lane & 32) != 0;
    #pragma unroll
    for (int q = 0; q < 2; q++) {
      float keep = bb ? v4[2+q] : v4[q];
      float send = bb ? v4[q]   : v4[2+q];
      v2[q] = keep + __shfl_xor(send, 32);
    }
  }
  const int k0 = ((m&1)<<4) | ((m&2)<<2) | (m&4) | ((m&8)>>2);
  float2 st; st.x = v2[0]; st.y = v2[1];
  *reinterpret_cast<float2*>(agg + (size_t)node*DM + hh*DHD + k0) = st;
}

// ---------------------------------------------------------------------------
// Final query MLP: 8 rows, 128->256->128->8, ELU, * NN_SCALE
// ---------------------------------------------------------------------------
__global__ __launch_bounds__(256) void mlp_kernel(
    const float* __restrict__ x, const int* __restrict__ qidx,
    const float* __restrict__ Wf1, const float* __restrict__ bf1,
    const float* __restrict__ Wf2, const float* __restrict__ bf2,
    const float* __restrict__ Wf3, const float* __restrict__ bf3,
    float* __restrict__ out) {
  __shared__ float xv[128];
  __shared__ float y1[256];
  __shared__ float y2[128];
  const int b = blockIdx.x, t = threadIdx.x;
  const int qi = qidx[b];
  if (t < 128) xv[t] = x[((size_t)b*NNODE + qi)*DM + t];
  __syncthreads();
  {
    float a1 = bf1[t];
    #pragma unroll 8
    for (int d = 0; d < 128; d++) a1 = fmaf(xv[d], Wf1[d*256 + t], a1);
    y1[t] = elu_f(a1);
  }
  __syncthreads();
  if (t < 128) {
    float a2 = bf2[t];
    #pragma unroll 8
    for (int d = 0; d < 256; d++) a2 = fmaf(y1[d], Wf2[d*128 + t], a2);
    y2[t] = elu_f(a2);
  }
  __syncthreads();
  if (t < 8) {
    float a3 = bf3[t];
    #pragma unroll 8
    for (int d = 0; d < 128; d++) a3 = fmaf(y2[d], Wf3[d*8 + t], a3);
    out[b*8 + t] = elu_f(a3) * NN_SCALE;
  }
}

// ---------------------------------------------------------------------------
extern "C" void kernel_launch(void* const* d_in, const int* in_sizes, int n_in,
                              void* d_out, int out_size, void* d_ws, size_t ws_size,
                              hipStream_t stream) {
  (void)in_sizes; (void)n_in; (void)out_size; (void)ws_size;
  const float* nf    = (const float*)d_in[0];
  const int*   qidx  = (const int*)d_in[1];
  const float* masks = (const float*)d_in[2];
  const int*   adj   = (const int*)d_in[3];
  // d_in[4] sim_results: unused by the reference
  const float* W0    = (const float*)d_in[5];
  const float* b0    = (const float*)d_in[6];
  const float* Wl    = (const float*)d_in[7];
  const float* a_src = (const float*)d_in[8];
  const float* a_dst = (const float*)d_in[9];
  const float* Wo    = (const float*)d_in[10];
  const float* Wlin  = (const float*)d_in[11];
  const float* blin  = (const float*)d_in[12];
  const float* ln_g  = (const float*)d_in[13];
  const float* ln_b  = (const float*)d_in[14];
  const float* Wf1   = (const float*)d_in[15];
  const float* bf1   = (const float*)d_in[16];
  const float* Wf2   = (const float*)d_in[17];
  const float* bf2   = (const float*)d_in[18];
  const float* Wf3   = (const float*)d_in[19];
  const float* bf3   = (const float*)d_in[20];

  float* ws  = (float*)d_ws;
  float* x   = ws + X_OFF;
  float* h   = ws + H_OFF;
  float* agg = ws + AGG_OFF;

  prep_kernel<<<48, 256, 0, stream>>>(Wl, Wo, Wlin, ws);

  // x = elu(nf @ W0 + b0)
  gemm_kernel<DIN, 1><<<BN/32, 128, 0, stream>>>(
      nf, W0, b0, nullptr, nullptr, nullptr, x);

  for (int l = 0; l < NLAYERS; l++) {
    const float* Wlp = ws + WLP_OFF   + l*DM*DM;
    const float* Wcb = ws + WCOMB_OFF + l*DM*DM;
    // h = x @ Wl  (all heads)
    gemm_kernel<DM, 0><<<BN/32, 128, 0, stream>>>(
        x, Wlp, nullptr, nullptr, nullptr, nullptr, h);
    // agg = GAT attention aggregate
    attn_kernel<<<BN/4, 256, 0, stream>>>(
        h, adj, masks, a_src + l*NH*DHD, a_dst + l*NH*DHD, agg);
    // x = LN(elu(agg @ Wcomb + blin) + x)
    gemm_kernel<DM, 2><<<BN/32, 128, 0, stream>>>(
        agg, Wcb, blin + l*DM, ln_g + l*DM, ln_b + l*DM, x, x);
  }

  mlp_kernel<<<8, 256, 0, stream>>>(
      x, qidx, Wf1, bf1, Wf2, bf2, Wf3, bf3, (float*)d_out);
}

// Round 13
// 402.501 us; speedup vs baseline: 1.3242x; 1.1920x over previous
//
#include <hip/hip_runtime.h>
#include <hip/hip_bf16.h>
#include <math.h>

#define BATCH 8
#define NNODE 4096
#define DEG 16
#define DIN 64
#define DM 128
#define NH 4
#define DHD 32
#define BN (BATCH*NNODE)   // 32768
#define NLAYERS 3
#define NN_SCALE 1999853.335557038f

// workspace layout (float offsets)
#define X_OFF     0
#define H_OFF     (BN*DM)
#define AGG_OFF   (2*BN*DM)
#define WLP_OFF   (3*BN*DM)
#define WCOMB_OFF (WLP_OFF + NLAYERS*DM*DM)

__device__ __forceinline__ float elu_f(float x) {
  return x > 0.f ? x : expm1f(x);
}

// ---------------------------------------------------------------------------
// Prep: Wl -> plain [d][c] layout;  Wcomb = blockdiag(Wo) @ Wlin  (128x128)
// ---------------------------------------------------------------------------
__global__ __launch_bounds__(256) void prep_kernel(
    const float* __restrict__ Wl, const float* __restrict__ Wo,
    const float* __restrict__ Wlin, float* __restrict__ ws) {
  const int bid = blockIdx.x;          // 48 blocks: l = bid>>4, slice = bid&15
  const int l = bid >> 4, sl = bid & 15;
  float* Wlp = ws + WLP_OFF   + l*DM*DM;
  float* Wcb = ws + WCOMB_OFF + l*DM*DM;
  const float* Wl_l   = Wl   + l*NH*DM*DHD;   // [h][d][k]
  const float* Wo_l   = Wo   + l*NH*DHD*DHD;  // [h][k][o]
  const float* Wlin_l = Wlin + l*DM*DM;       // [c'][d]
  for (int idx = sl*1024 + threadIdx.x; idx < (sl+1)*1024; idx += 256) {
    int d = idx >> 7, c = idx & 127;
    Wlp[idx] = Wl_l[((c>>5)*DM + d)*DHD + (c&31)];
  }
  for (int idx = sl*1024 + threadIdx.x; idx < (sl+1)*1024; idx += 256) {
    int r = idx >> 7, dcol = idx & 127;
    int h = r >> 5, k = r & 31;
    const float* wo  = Wo_l + (h*DHD + k)*DHD;      // over o
    const float* wl2 = Wlin_l + (h*DHD)*DM + dcol;  // stride DM over o
    float acc = 0.f;
    #pragma unroll
    for (int o = 0; o < DHD; o++) acc = fmaf(wo[o], wl2[o*DM], acc);
    Wcb[idx] = acc;
  }
}

// ---------------------------------------------------------------------------
// Tall GEMM v3: out[BN x 128] = A[BN x K] @ W[K x 128]  (+ epilogue)
// Register-prefetch pipeline: chunk k+1 global->reg loads issue right after
// the post-write barrier, latency hides under the 2048-cy FMA block.
// 128 thr = 8(i) x 16(j), 4 rows x 8 cols/thread, 32-row tile, grid 1024.
// XCD-clustered: bid&7 = batch (validated by R12 FETCH_SIZE 6x drop).
// ---------------------------------------------------------------------------
template<int K, int EPI>
__global__ __launch_bounds__(128) void gemm_kernel(
    const float* __restrict__ A, const float* __restrict__ W,
    const float* __restrict__ bias, const float* __restrict__ lng,
    const float* __restrict__ lnb, const float* __restrict__ res,
    float* __restrict__ out) {
  __shared__ float xT[32][36];    // transposed A chunk (k x row)
  __shared__ float Wc[32][132];   // W chunk (k x col)
  const int tid = threadIdx.x;
  const int j = tid & 15, i = tid >> 4;
  const int bid  = blockIdx.x;
  const int row0 = ((bid & 7) * 128 + (bid >> 3)) * 32;

  float acc[4][8];
  #pragma unroll
  for (int a = 0; a < 4; a++)
    #pragma unroll
    for (int b = 0; b < 8; b++) acc[a][b] = 0.f;

  float bval[8], gv[8], bv2[8];
  if (EPI != 0) {
    #pragma unroll
    for (int cc = 0; cc < 8; cc++) bval[cc] = bias[j*8 + cc];
  }
  if (EPI == 2) {
    #pragma unroll
    for (int cc = 0; cc < 8; cc++) { gv[cc] = lng[j*8+cc]; bv2[cc] = lnb[j*8+cc]; }
  }

  const int kq = tid & 7, rb = tid >> 3;

  // prologue: stage chunk 0 into registers
  float4 aR[2], wR[8];
  #pragma unroll
  for (int p = 0; p < 2; p++)
    aR[p] = *reinterpret_cast<const float4*>(
        &A[(size_t)(row0 + rb + p*16)*K + kq*4]);
  #pragma unroll
  for (int p = 0; p < 8; p++) {
    const int idx = p*128 + tid;
    const int d = idx >> 5, cq = idx & 31;
    wR[p] = *reinterpret_cast<const float4*>(&W[(size_t)d*128 + cq*4]);
  }

  for (int k0 = 0; k0 < K; k0 += 32) {
    __syncthreads();               // prev compute done; LDS free
    #pragma unroll
    for (int p = 0; p < 2; p++) {
      const int r = rb + p*16;
      xT[kq*4+0][r] = aR[p].x; xT[kq*4+1][r] = aR[p].y;
      xT[kq*4+2][r] = aR[p].z; xT[kq*4+3][r] = aR[p].w;
    }
    #pragma unroll
    for (int p = 0; p < 8; p++) {
      const int idx = p*128 + tid;
      const int d = idx >> 5, cq = idx & 31;
      *reinterpret_cast<float4*>(&Wc[d][cq*4]) = wR[p];
    }
    __syncthreads();
    if (k0 + 32 < K) {             // prefetch next chunk (in flight over compute)
      #pragma unroll
      for (int p = 0; p < 2; p++)
        aR[p] = *reinterpret_cast<const float4*>(
            &A[(size_t)(row0 + rb + p*16)*K + (k0 + 32) + kq*4]);
      #pragma unroll
      for (int p = 0; p < 8; p++) {
        const int idx = p*128 + tid;
        const int d = idx >> 5, cq = idx & 31;
        wR[p] = *reinterpret_cast<const float4*>(
            &W[(size_t)(k0 + 32 + d)*128 + cq*4]);
      }
    }
    #pragma unroll
    for (int kk = 0; kk < 32; kk++) {
      const float4 a0 = *reinterpret_cast<const float4*>(&xT[kk][i*4]);
      const float av[4] = {a0.x, a0.y, a0.z, a0.w};
      const float4 w0 = *reinterpret_cast<const float4*>(&Wc[kk][j*8]);
      const float4 w1 = *reinterpret_cast<const float4*>(&Wc[kk][j*8+4]);
      const float wv[8] = {w0.x,w0.y,w0.z,w0.w,w1.x,w1.y,w1.z,w1.w};
      #pragma unroll
      for (int rr = 0; rr < 4; rr++)
        #pragma unroll
        for (int cc = 0; cc < 8; cc++)
          acc[rr][cc] = fmaf(av[rr], wv[cc], acc[rr][cc]);
    }
  }

  if (EPI == 0) {
    #pragma unroll
    for (int rr = 0; rr < 4; rr++) {
      float* op = out + (size_t)(row0 + i*4 + rr)*DM + j*8;
      float4 v0 = {acc[rr][0],acc[rr][1],acc[rr][2],acc[rr][3]};
      float4 v1 = {acc[rr][4],acc[rr][5],acc[rr][6],acc[rr][7]};
      *reinterpret_cast<float4*>(op)     = v0;
      *reinterpret_cast<float4*>(op + 4) = v1;
    }
  } else if (EPI == 1) {
    #pragma unroll
    for (int rr = 0; rr < 4; rr++) {
      float* op = out + (size_t)(row0 + i*4 + rr)*DM + j*8;
      float4 v0, v1;
      v0.x = elu_f(acc[rr][0]+bval[0]); v0.y = elu_f(acc[rr][1]+bval[1]);
      v0.z = elu_f(acc[rr][2]+bval[2]); v0.w = elu_f(acc[rr][3]+bval[3]);
      v1.x = elu_f(acc[rr][4]+bval[4]); v1.y = elu_f(acc[rr][5]+bval[5]);
      v1.z = elu_f(acc[rr][6]+bval[6]); v1.w = elu_f(acc[rr][7]+bval[7]);
      *reinterpret_cast<float4*>(op)     = v0;
      *reinterpret_cast<float4*>(op + 4) = v1;
    }
  } else {
    float s[4], s2[4];
    #pragma unroll
    for (int rr = 0; rr < 4; rr++) {
      const int r = row0 + i*4 + rr;
      const float4 r0 = *reinterpret_cast<const float4*>(&res[(size_t)r*DM + j*8]);
      const float4 r1 = *reinterpret_cast<const float4*>(&res[(size_t)r*DM + j*8 + 4]);
      const float rv[8] = {r0.x,r0.y,r0.z,r0.w,r1.x,r1.y,r1.z,r1.w};
      s[rr] = 0.f; s2[rr] = 0.f;
      #pragma unroll
      for (int cc = 0; cc < 8; cc++) {
        float v = elu_f(acc[rr][cc] + bval[cc]) + rv[cc];
        acc[rr][cc] = v; s[rr] += v; s2[rr] += v*v;
      }
    }
    #pragma unroll
    for (int o = 1; o < 16; o <<= 1) {
      #pragma unroll
      for (int rr = 0; rr < 4; rr++) {
        s[rr]  += __shfl_xor(s[rr],  o);
        s2[rr] += __shfl_xor(s2[rr], o);
      }
    }
    #pragma unroll
    for (int rr = 0; rr < 4; rr++) {
      const int r = row0 + i*4 + rr;
      const float mu  = s[rr] * (1.f/128.f);
      const float var = s2[rr] * (1.f/128.f) - mu*mu;
      const float rs  = rsqrtf(var + 1e-5f);
      float4 v0, v1;
      v0.x = (acc[rr][0]-mu)*rs*gv[0] + bv2[0];
      v0.y = (acc[rr][1]-mu)*rs*gv[1] + bv2[1];
      v0.z = (acc[rr][2]-mu)*rs*gv[2] + bv2[2];
      v0.w = (acc[rr][3]-mu)*rs*gv[3] + bv2[3];
      v1.x = (acc[rr][4]-mu)*rs*gv[4] + bv2[4];
      v1.y = (acc[rr][5]-mu)*rs*gv[5] + bv2[5];
      v1.z = (acc[rr][6]-mu)*rs*gv[6] + bv2[6];
      v1.w = (acc[rr][7]-mu)*rs*gv[7] + bv2[7];
      float* op = out + (size_t)r*DM + j*8;
      *reinterpret_cast<float4*>(op)     = v0;
      *reinterpret_cast<float4*>(op + 4) = v1;
    }
  }
}

// ---------------------------------------------------------------------------
// Attention v3: chunk-major lanes for COALESCED gathers.
// Wave per node. lane = (half, c): half = m parity, c = 16B chunk of row.
// Per gather instr: 2 rows x 8 lines (was 64 lines). Dot products reduce
// within 8-lane chunk groups (head hd = c>>3); softmax/agg combine halves
// via one shfl_xor(32).
// ---------------------------------------------------------------------------
__global__ __launch_bounds__(256) void attn_kernel(
    const float* __restrict__ h, const int* __restrict__ adj,
    const float* __restrict__ masks, const float* __restrict__ a_src,
    const float* __restrict__ a_dst, float* __restrict__ agg) {
  const int lane = threadIdx.x & 63;
  const int wid  = threadIdx.x >> 6;
  const int bid  = blockIdx.x;                       // 8192 blocks
  const int node = ((bid & 7) << 12) + ((bid >> 3) << 2) + wid;
  const int b    = node >> 12;
  const int half = lane >> 5;     // neighbor parity
  const int c    = lane & 31;     // chunk (4 floats) within 128-float row

  // a_src/a_dst flatten: head (c>>3), pos (c&7)*4  ==  flat offset 4c
  const float4 asr4 = *reinterpret_cast<const float4*>(a_src + 4*c);
  const float4 ad4  = *reinterpret_cast<const float4*>(a_dst + 4*c);

  // e_src(head of this lane): chunk dot + 8-lane group reduce
  const float4 hv = *reinterpret_cast<const float4*>(h + (size_t)node*DM + 4*c);
  float es = hv.x*asr4.x + hv.y*asr4.y + hv.z*asr4.z + hv.w*asr4.w;
  es += __shfl_xor(es, 1); es += __shfl_xor(es, 2); es += __shfl_xor(es, 4);

  float4 v[8]; float e[8];
  #pragma unroll
  for (int i = 0; i < 8; i++) {
    const int m  = 2*i + half;
    const int jn = adj[node*DEG + m];
    const float mval = masks[node*DEG + m];
    v[i] = *reinterpret_cast<const float4*>(
        h + ((size_t)(b*NNODE + jn))*DM + 4*c);              // coalesced 512B/half-wave
    float ed = v[i].x*ad4.x + v[i].y*ad4.y + v[i].z*ad4.z + v[i].w*ad4.w;
    ed += __shfl_xor(ed, 1); ed += __shfl_xor(ed, 2); ed += __shfl_xor(ed, 4);
    float t = es + ed;
    t = t > 0.f ? t : 0.2f*t;        // leaky_relu 0.2
    e[i] = (mval > 0.f) ? t : -1e9f; // mask
  }

  // softmax over 16 neighbors: own 8 + cross-half combine
  float mx = e[0];
  #pragma unroll
  for (int i = 1; i < 8; i++) mx = fmaxf(mx, e[i]);
  mx = fmaxf(mx, __shfl_xor(mx, 32));
  float s = 0.f;
  #pragma unroll
  for (int i = 0; i < 8; i++) { e[i] = __expf(e[i] - mx); s += e[i]; }
  s += __shfl_xor(s, 32);
  const float inv = 1.f / s;

  float4 acc = {0.f, 0.f, 0.f, 0.f};
  #pragma unroll
  for (int i = 0; i < 8; i++) {
    const float a = e[i] * inv;
    acc.x = fmaf(a, v[i].x, acc.x); acc.y = fmaf(a, v[i].y, acc.y);
    acc.z = fmaf(a, v[i].z, acc.z); acc.w = fmaf(a, v[i].w, acc.w);
  }
  acc.x += __shfl_xor(acc.x, 32); acc.y += __shfl_xor(acc.y, 32);
  acc.z += __shfl_xor(acc.z, 32); acc.w += __shfl_xor(acc.w, 32);

  if (half == 0)
    *reinterpret_cast<float4*>(agg + (size_t)node*DM + 4*c) = acc;  // 512B coalesced
}

// ---------------------------------------------------------------------------
// Final query MLP: 8 rows, 128->256->128->8, ELU, * NN_SCALE
// ---------------------------------------------------------------------------
__global__ __launch_bounds__(256) void mlp_kernel(
    const float* __restrict__ x, const int* __restrict__ qidx,
    const float* __restrict__ Wf1, const float* __restrict__ bf1,
    const float* __restrict__ Wf2, const float* __restrict__ bf2,
    const float* __restrict__ Wf3, const float* __restrict__ bf3,
    float* __restrict__ out) {
  __shared__ float xv[128];
  __shared__ float y1[256];
  __shared__ float y2[128];
  const int b = blockIdx.x, t = threadIdx.x;
  const int qi = qidx[b];
  if (t < 128) xv[t] = x[((size_t)b*NNODE + qi)*DM + t];
  __syncthreads();
  {
    float a1 = bf1[t];
    #pragma unroll 8
    for (int d = 0; d < 128; d++) a1 = fmaf(xv[d], Wf1[d*256 + t], a1);
    y1[t] = elu_f(a1);
  }
  __syncthreads();
  if (t < 128) {
    float a2 = bf2[t];
    #pragma unroll 8
    for (int d = 0; d < 256; d++) a2 = fmaf(y1[d], Wf2[d*128 + t], a2);
    y2[t] = elu_f(a2);
  }
  __syncthreads();
  if (t < 8) {
    float a3 = bf3[t];
    #pragma unroll 8
    for (int d = 0; d < 128; d++) a3 = fmaf(y2[d], Wf3[d*8 + t], a3);
    out[b*8 + t] = elu_f(a3) * NN_SCALE;
  }
}

// ---------------------------------------------------------------------------
extern "C" void kernel_launch(void* const* d_in, const int* in_sizes, int n_in,
                              void* d_out, int out_size, void* d_ws, size_t ws_size,
                              hipStream_t stream) {
  (void)in_sizes; (void)n_in; (void)out_size; (void)ws_size;
  const float* nf    = (const float*)d_in[0];
  const int*   qidx  = (const int*)d_in[1];
  const float* masks = (const float*)d_in[2];
  const int*   adj   = (const int*)d_in[3];
  // d_in[4] sim_results: unused by the reference
  const float* W0    = (const float*)d_in[5];
  const float* b0    = (const float*)d_in[6];
  const float* Wl    = (const float*)d_in[7];
  const float* a_src = (const float*)d_in[8];
  const float* a_dst = (const float*)d_in[9];
  const float* Wo    = (const float*)d_in[10];
  const float* Wlin  = (const float*)d_in[11];
  const float* blin  = (const float*)d_in[12];
  const float* ln_g  = (const float*)d_in[13];
  const float* ln_b  = (const float*)d_in[14];
  const float* Wf1   = (const float*)d_in[15];
  const float* bf1   = (const float*)d_in[16];
  const float* Wf2   = (const float*)d_in[17];
  const float* bf2   = (const float*)d_in[18];
  const float* Wf3   = (const float*)d_in[19];
  const float* bf3   = (const float*)d_in[20];

  float* ws  = (float*)d_ws;
  float* x   = ws + X_OFF;
  float* h   = ws + H_OFF;
  float* agg = ws + AGG_OFF;

  prep_kernel<<<48, 256, 0, stream>>>(Wl, Wo, Wlin, ws);

  // x = elu(nf @ W0 + b0)
  gemm_kernel<DIN, 1><<<BN/32, 128, 0, stream>>>(
      nf, W0, b0, nullptr, nullptr, nullptr, x);

  for (int l = 0; l < NLAYERS; l++) {
    const float* Wlp = ws + WLP_OFF   + l*DM*DM;
    const float* Wcb = ws + WCOMB_OFF + l*DM*DM;
    // h = x @ Wl  (all heads)
    gemm_kernel<DM, 0><<<BN/32, 128, 0, stream>>>(
        x, Wlp, nullptr, nullptr, nullptr, nullptr, h);
    // agg = GAT attention aggregate
    attn_kernel<<<BN/4, 256, 0, stream>>>(
        h, adj, masks, a_src + l*NH*DHD, a_dst + l*NH*DHD, agg);
    // x = LN(elu(agg @ Wcomb + blin) + x)
    gemm_kernel<DM, 2><<<BN/32, 128, 0, stream>>>(
        agg, Wcb, blin + l*DM, ln_g + l*DM, ln_b + l*DM, x, x);
  }

  mlp_kernel<<<8, 256, 0, stream>>>(
      x, qidx, Wf1, bf1, Wf2, bf2, Wf3, bf3, (float*)d_out);
}

// Round 14
// 372.915 us; speedup vs baseline: 1.4292x; 1.0793x over previous
//
#include <hip/hip_runtime.h>
#include <hip/hip_bf16.h>
#include <math.h>

#define BATCH 8
#define NNODE 4096
#define DEG 16
#define DIN 64
#define DM 128
#define NH 4
#define DHD 32
#define BN (BATCH*NNODE)   // 32768
#define NLAYERS 3
#define NN_SCALE 1999853.335557038f

// workspace layout (float offsets)
#define X_OFF     0
#define H_OFF     (BN*DM)
#define WLP_OFF   (2*BN*DM)
#define WCOMB_OFF (WLP_OFF + NLAYERS*DM*DM)

__device__ __forceinline__ float elu_f(float x) {
  return x > 0.f ? x : expm1f(x);
}

// ---------------------------------------------------------------------------
// Prep: Wl -> plain [d][c] layout;  Wcomb = blockdiag(Wo) @ Wlin  (128x128)
// ---------------------------------------------------------------------------
__global__ __launch_bounds__(256) void prep_kernel(
    const float* __restrict__ Wl, const float* __restrict__ Wo,
    const float* __restrict__ Wlin, float* __restrict__ ws) {
  const int bid = blockIdx.x;          // 48 blocks: l = bid>>4, slice = bid&15
  const int l = bid >> 4, sl = bid & 15;
  float* Wlp = ws + WLP_OFF   + l*DM*DM;
  float* Wcb = ws + WCOMB_OFF + l*DM*DM;
  const float* Wl_l   = Wl   + l*NH*DM*DHD;   // [h][d][k]
  const float* Wo_l   = Wo   + l*NH*DHD*DHD;  // [h][k][o]
  const float* Wlin_l = Wlin + l*DM*DM;       // [c'][d]
  for (int idx = sl*1024 + threadIdx.x; idx < (sl+1)*1024; idx += 256) {
    int d = idx >> 7, c = idx & 127;
    Wlp[idx] = Wl_l[((c>>5)*DM + d)*DHD + (c&31)];
  }
  for (int idx = sl*1024 + threadIdx.x; idx < (sl+1)*1024; idx += 256) {
    int r = idx >> 7, dcol = idx & 127;
    int h = r >> 5, k = r & 31;
    const float* wo  = Wo_l + (h*DHD + k)*DHD;      // over o
    const float* wl2 = Wlin_l + (h*DHD)*DM + dcol;  // stride DM over o
    float acc = 0.f;
    #pragma unroll
    for (int o = 0; o < DHD; o++) acc = fmaf(wo[o], wl2[o*DM], acc);
    Wcb[idx] = acc;
  }
}

// ---------------------------------------------------------------------------
// Tall GEMM (EPI 0 plain / 1 bias+ELU): out[BN x 128] = A[BN x K] @ W[K x 128]
// Register-prefetch pipeline, 32-row tile, grid 1024, XCD-clustered (bid&7).
// ---------------------------------------------------------------------------
template<int K, int EPI>
__global__ __launch_bounds__(128) void gemm_kernel(
    const float* __restrict__ A, const float* __restrict__ W,
    const float* __restrict__ bias, float* __restrict__ out) {
  __shared__ float xT[32][36];    // transposed A chunk (k x row)
  __shared__ float Wc[32][132];   // W chunk (k x col)
  const int tid = threadIdx.x;
  const int j = tid & 15, i = tid >> 4;
  const int bid  = blockIdx.x;
  const int row0 = ((bid & 7) * 128 + (bid >> 3)) * 32;

  float acc[4][8];
  #pragma unroll
  for (int a = 0; a < 4; a++)
    #pragma unroll
    for (int b = 0; b < 8; b++) acc[a][b] = 0.f;

  float bval[8];
  if (EPI != 0) {
    #pragma unroll
    for (int cc = 0; cc < 8; cc++) bval[cc] = bias[j*8 + cc];
  }

  const int kq = tid & 7, rb = tid >> 3;

  float4 aR[2], wR[8];
  #pragma unroll
  for (int p = 0; p < 2; p++)
    aR[p] = *reinterpret_cast<const float4*>(
        &A[(size_t)(row0 + rb + p*16)*K + kq*4]);
  #pragma unroll
  for (int p = 0; p < 8; p++) {
    const int idx = p*128 + tid;
    const int d = idx >> 5, cq = idx & 31;
    wR[p] = *reinterpret_cast<const float4*>(&W[(size_t)d*128 + cq*4]);
  }

  for (int k0 = 0; k0 < K; k0 += 32) {
    __syncthreads();
    #pragma unroll
    for (int p = 0; p < 2; p++) {
      const int r = rb + p*16;
      xT[kq*4+0][r] = aR[p].x; xT[kq*4+1][r] = aR[p].y;
      xT[kq*4+2][r] = aR[p].z; xT[kq*4+3][r] = aR[p].w;
    }
    #pragma unroll
    for (int p = 0; p < 8; p++) {
      const int idx = p*128 + tid;
      const int d = idx >> 5, cq = idx & 31;
      *reinterpret_cast<float4*>(&Wc[d][cq*4]) = wR[p];
    }
    __syncthreads();
    if (k0 + 32 < K) {
      #pragma unroll
      for (int p = 0; p < 2; p++)
        aR[p] = *reinterpret_cast<const float4*>(
            &A[(size_t)(row0 + rb + p*16)*K + (k0 + 32) + kq*4]);
      #pragma unroll
      for (int p = 0; p < 8; p++) {
        const int idx = p*128 + tid;
        const int d = idx >> 5, cq = idx & 31;
        wR[p] = *reinterpret_cast<const float4*>(
            &W[(size_t)(k0 + 32 + d)*128 + cq*4]);
      }
    }
    #pragma unroll
    for (int kk = 0; kk < 32; kk++) {
      const float4 a0 = *reinterpret_cast<const float4*>(&xT[kk][i*4]);
      const float av[4] = {a0.x, a0.y, a0.z, a0.w};
      const float4 w0 = *reinterpret_cast<const float4*>(&Wc[kk][j*8]);
      const float4 w1 = *reinterpret_cast<const float4*>(&Wc[kk][j*8+4]);
      const float wv[8] = {w0.x,w0.y,w0.z,w0.w,w1.x,w1.y,w1.z,w1.w};
      #pragma unroll
      for (int rr = 0; rr < 4; rr++)
        #pragma unroll
        for (int cc = 0; cc < 8; cc++)
          acc[rr][cc] = fmaf(av[rr], wv[cc], acc[rr][cc]);
    }
  }

  #pragma unroll
  for (int rr = 0; rr < 4; rr++) {
    float* op = out + (size_t)(row0 + i*4 + rr)*DM + j*8;
    float4 v0, v1;
    if (EPI == 0) {
      v0 = make_float4(acc[rr][0],acc[rr][1],acc[rr][2],acc[rr][3]);
      v1 = make_float4(acc[rr][4],acc[rr][5],acc[rr][6],acc[rr][7]);
    } else {
      v0.x = elu_f(acc[rr][0]+bval[0]); v0.y = elu_f(acc[rr][1]+bval[1]);
      v0.z = elu_f(acc[rr][2]+bval[2]); v0.w = elu_f(acc[rr][3]+bval[3]);
      v1.x = elu_f(acc[rr][4]+bval[4]); v1.y = elu_f(acc[rr][5]+bval[5]);
      v1.z = elu_f(acc[rr][6]+bval[6]); v1.w = elu_f(acc[rr][7]+bval[7]);
    }
    *reinterpret_cast<float4*>(op)     = v0;
    *reinterpret_cast<float4*>(op + 4) = v1;
  }
}

// ---------------------------------------------------------------------------
// FUSED attn + out-GEMM + bias/ELU/residual/LN.  One block = 32 nodes.
// Phase 1: v3 attn (wave per node, half/chunk lanes) -> agg tile in LDS.
// Phase 2: x[tile] = LN(elu(agg @ Wcomb + blin) + x[tile]).
// XCD-clustered: bid&7 = batch; h gathers stay in that XCD's L2.
// ---------------------------------------------------------------------------
__global__ __launch_bounds__(256) void fused_attn_out_kernel(
    const float* __restrict__ h, const int* __restrict__ adj,
    const float* __restrict__ masks, const float* __restrict__ a_src,
    const float* __restrict__ a_dst, const float* __restrict__ Wcb,
    const float* __restrict__ blin, const float* __restrict__ lng,
    const float* __restrict__ lnb, float* __restrict__ x) {
  __shared__ float agg_s[32][132];   // attn output tile (padded)
  __shared__ float Wc[32][132];      // Wcomb chunk
  const int tid  = threadIdx.x;
  const int bid  = blockIdx.x;                 // 1024 blocks
  const int node0 = ((bid & 7) * 128 + (bid >> 3)) * 32;
  const int b     = node0 >> 12;

  // ---- phase 1: attention, 4 waves x 8 nodes ----
  {
    const int lane = tid & 63;
    const int wid  = tid >> 6;
    const int half = lane >> 5;
    const int c    = lane & 31;
    const float4 asr4 = *reinterpret_cast<const float4*>(a_src + 4*c);
    const float4 ad4  = *reinterpret_cast<const float4*>(a_dst + 4*c);

    for (int it = 0; it < 8; ++it) {
      const int nl   = wid*8 + it;        // local node 0..31
      const int node = node0 + nl;

      const float4 hv = *reinterpret_cast<const float4*>(
          h + (size_t)node*DM + 4*c);
      float es = hv.x*asr4.x + hv.y*asr4.y + hv.z*asr4.z + hv.w*asr4.w;
      es += __shfl_xor(es, 1); es += __shfl_xor(es, 2); es += __shfl_xor(es, 4);

      float4 v[8]; float e[8];
      #pragma unroll
      for (int i = 0; i < 8; i++) {
        const int m  = 2*i + half;
        const int jn = adj[node*DEG + m];
        const float mval = masks[node*DEG + m];
        v[i] = *reinterpret_cast<const float4*>(
            h + ((size_t)(b*NNODE + jn))*DM + 4*c);
        float ed = v[i].x*ad4.x + v[i].y*ad4.y + v[i].z*ad4.z + v[i].w*ad4.w;
        ed += __shfl_xor(ed, 1); ed += __shfl_xor(ed, 2); ed += __shfl_xor(ed, 4);
        float t = es + ed;
        t = t > 0.f ? t : 0.2f*t;
        e[i] = (mval > 0.f) ? t : -1e9f;
      }

      float mx = e[0];
      #pragma unroll
      for (int i = 1; i < 8; i++) mx = fmaxf(mx, e[i]);
      mx = fmaxf(mx, __shfl_xor(mx, 32));
      float s = 0.f;
      #pragma unroll
      for (int i = 0; i < 8; i++) { e[i] = __expf(e[i] - mx); s += e[i]; }
      s += __shfl_xor(s, 32);
      const float inv = 1.f / s;

      float4 acc = {0.f, 0.f, 0.f, 0.f};
      #pragma unroll
      for (int i = 0; i < 8; i++) {
        const float a = e[i] * inv;
        acc.x = fmaf(a, v[i].x, acc.x); acc.y = fmaf(a, v[i].y, acc.y);
        acc.z = fmaf(a, v[i].z, acc.z); acc.w = fmaf(a, v[i].w, acc.w);
      }
      acc.x += __shfl_xor(acc.x, 32); acc.y += __shfl_xor(acc.y, 32);
      acc.z += __shfl_xor(acc.z, 32); acc.w += __shfl_xor(acc.w, 32);

      if (half == 0)
        *reinterpret_cast<float4*>(&agg_s[nl][4*c]) = acc;
    }
  }
  __syncthreads();

  // ---- phase 2: out-GEMM + bias/ELU/residual/LN ----
  const int j = tid & 15, i = tid >> 4;       // j 0..15 colgrp, i 0..15 rowgrp
  float bval[8], gv[8], bv2[8];
  #pragma unroll
  for (int cc = 0; cc < 8; cc++) {
    bval[cc] = blin[j*8+cc]; gv[cc] = lng[j*8+cc]; bv2[cc] = lnb[j*8+cc];
  }

  float acc[2][8];
  #pragma unroll
  for (int a = 0; a < 2; a++)
    #pragma unroll
    for (int bb = 0; bb < 8; bb++) acc[a][bb] = 0.f;

  for (int k0 = 0; k0 < DM; k0 += 32) {
    __syncthreads();
    #pragma unroll
    for (int p = 0; p < 4; p++) {
      const int idx = p*256 + tid;            // 0..1023 float4 quads
      const int d = idx >> 5, cq = idx & 31;
      *reinterpret_cast<float4*>(&Wc[d][cq*4]) =
          *reinterpret_cast<const float4*>(&Wcb[(size_t)(k0 + d)*128 + cq*4]);
    }
    __syncthreads();
    #pragma unroll
    for (int kk = 0; kk < 32; kk++) {
      const float a0 = agg_s[i*2+0][k0+kk];
      const float a1 = agg_s[i*2+1][k0+kk];
      const float4 w0 = *reinterpret_cast<const float4*>(&Wc[kk][j*8]);
      const float4 w1 = *reinterpret_cast<const float4*>(&Wc[kk][j*8+4]);
      const float wv[8] = {w0.x,w0.y,w0.z,w0.w,w1.x,w1.y,w1.z,w1.w};
      #pragma unroll
      for (int cc = 0; cc < 8; cc++) {
        acc[0][cc] = fmaf(a0, wv[cc], acc[0][cc]);
        acc[1][cc] = fmaf(a1, wv[cc], acc[1][cc]);
      }
    }
  }

  float s[2], s2[2];
  #pragma unroll
  for (int rr = 0; rr < 2; rr++) {
    const int r = node0 + i*2 + rr;
    const float4 r0 = *reinterpret_cast<const float4*>(&x[(size_t)r*DM + j*8]);
    const float4 r1 = *reinterpret_cast<const float4*>(&x[(size_t)r*DM + j*8 + 4]);
    const float rv[8] = {r0.x,r0.y,r0.z,r0.w,r1.x,r1.y,r1.z,r1.w};
    s[rr] = 0.f; s2[rr] = 0.f;
    #pragma unroll
    for (int cc = 0; cc < 8; cc++) {
      float v = elu_f(acc[rr][cc] + bval[cc]) + rv[cc];
      acc[rr][cc] = v; s[rr] += v; s2[rr] += v*v;
    }
  }
  #pragma unroll
  for (int o = 1; o < 16; o <<= 1) {
    #pragma unroll
    for (int rr = 0; rr < 2; rr++) {
      s[rr]  += __shfl_xor(s[rr],  o);
      s2[rr] += __shfl_xor(s2[rr], o);
    }
  }
  #pragma unroll
  for (int rr = 0; rr < 2; rr++) {
    const int r = node0 + i*2 + rr;
    const float mu  = s[rr] * (1.f/128.f);
    const float var = s2[rr] * (1.f/128.f) - mu*mu;
    const float rs  = rsqrtf(var + 1e-5f);
    float4 v0, v1;
    v0.x = (acc[rr][0]-mu)*rs*gv[0] + bv2[0];
    v0.y = (acc[rr][1]-mu)*rs*gv[1] + bv2[1];
    v0.z = (acc[rr][2]-mu)*rs*gv[2] + bv2[2];
    v0.w = (acc[rr][3]-mu)*rs*gv[3] + bv2[3];
    v1.x = (acc[rr][4]-mu)*rs*gv[4] + bv2[4];
    v1.y = (acc[rr][5]-mu)*rs*gv[5] + bv2[5];
    v1.z = (acc[rr][6]-mu)*rs*gv[6] + bv2[6];
    v1.w = (acc[rr][7]-mu)*rs*gv[7] + bv2[7];
    float* op = x + (size_t)r*DM + j*8;
    *reinterpret_cast<float4*>(op)     = v0;
    *reinterpret_cast<float4*>(op + 4) = v1;
  }
}

// ---------------------------------------------------------------------------
// Final query MLP: 8 rows, 128->256->128->8, ELU, * NN_SCALE
// ---------------------------------------------------------------------------
__global__ __launch_bounds__(256) void mlp_kernel(
    const float* __restrict__ x, const int* __restrict__ qidx,
    const float* __restrict__ Wf1, const float* __restrict__ bf1,
    const float* __restrict__ Wf2, const float* __restrict__ bf2,
    const float* __restrict__ Wf3, const float* __restrict__ bf3,
    float* __restrict__ out) {
  __shared__ float xv[128];
  __shared__ float y1[256];
  __shared__ float y2[128];
  const int b = blockIdx.x, t = threadIdx.x;
  const int qi = qidx[b];
  if (t < 128) xv[t] = x[((size_t)b*NNODE + qi)*DM + t];
  __syncthreads();
  {
    float a1 = bf1[t];
    #pragma unroll 8
    for (int d = 0; d < 128; d++) a1 = fmaf(xv[d], Wf1[d*256 + t], a1);
    y1[t] = elu_f(a1);
  }
  __syncthreads();
  if (t < 128) {
    float a2 = bf2[t];
    #pragma unroll 8
    for (int d = 0; d < 256; d++) a2 = fmaf(y1[d], Wf2[d*128 + t], a2);
    y2[t] = elu_f(a2);
  }
  __syncthreads();
  if (t < 8) {
    float a3 = bf3[t];
    #pragma unroll 8
    for (int d = 0; d < 128; d++) a3 = fmaf(y2[d], Wf3[d*8 + t], a3);
    out[b*8 + t] = elu_f(a3) * NN_SCALE;
  }
}

// ---------------------------------------------------------------------------
extern "C" void kernel_launch(void* const* d_in, const int* in_sizes, int n_in,
                              void* d_out, int out_size, void* d_ws, size_t ws_size,
                              hipStream_t stream) {
  (void)in_sizes; (void)n_in; (void)out_size; (void)ws_size;
  const float* nf    = (const float*)d_in[0];
  const int*   qidx  = (const int*)d_in[1];
  const float* masks = (const float*)d_in[2];
  const int*   adj   = (const int*)d_in[3];
  // d_in[4] sim_results: unused by the reference
  const float* W0    = (const float*)d_in[5];
  const float* b0    = (const float*)d_in[6];
  const float* Wl    = (const float*)d_in[7];
  const float* a_src = (const float*)d_in[8];
  const float* a_dst = (const float*)d_in[9];
  const float* Wo    = (const float*)d_in[10];
  const float* Wlin  = (const float*)d_in[11];
  const float* blin  = (const float*)d_in[12];
  const float* ln_g  = (const float*)d_in[13];
  const float* ln_b  = (const float*)d_in[14];
  const float* Wf1   = (const float*)d_in[15];
  const float* bf1   = (const float*)d_in[16];
  const float* Wf2   = (const float*)d_in[17];
  const float* bf2   = (const float*)d_in[18];
  const float* Wf3   = (const float*)d_in[19];
  const float* bf3   = (const float*)d_in[20];

  float* ws = (float*)d_ws;
  float* x  = ws + X_OFF;
  float* h  = ws + H_OFF;

  prep_kernel<<<48, 256, 0, stream>>>(Wl, Wo, Wlin, ws);

  // x = elu(nf @ W0 + b0)
  gemm_kernel<DIN, 1><<<BN/32, 128, 0, stream>>>(nf, W0, b0, x);

  for (int l = 0; l < NLAYERS; l++) {
    const float* Wlp = ws + WLP_OFF   + l*DM*DM;
    const float* Wcb = ws + WCOMB_OFF + l*DM*DM;
    // h = x @ Wl  (all heads)
    gemm_kernel<DM, 0><<<BN/32, 128, 0, stream>>>(x, Wlp, nullptr, h);
    // x = LN(elu(attn(h) @ Wcomb + blin) + x)   [fused]
    fused_attn_out_kernel<<<BN/32, 256, 0, stream>>>(
        h, adj, masks, a_src + l*NH*DHD, a_dst + l*NH*DHD,
        Wcb, blin + l*DM, ln_g + l*DM, ln_b + l*DM, x);
  }

  mlp_kernel<<<8, 256, 0, stream>>>(
      x, qidx, Wf1, bf1, Wf2, bf2, Wf3, bf3, (float*)d_out);
}